// Round 8
// baseline (3130.616 us; speedup 1.0000x reference)
//
#include <hip/hip_runtime.h>
#include <hip/hip_bf16.h>

#define DEPTH 24
#define DM 192
#define DI 384
#define DS 16
#define DR 12
#define LSEQ 401
#define BATCH 4
#define NTOK (BATCH*LSEQ)          // 1604
#define NCLS 22
#define NC 16                      // scan time-chunks
#define TCH 26                     // ceil(401/16); last chunk = 11

__device__ __forceinline__ float silu_f(float x) { return x / (1.f + __expf(-x)); }

// ---------------- patch embed + cls + pos; 4 tokens per block; zeroes dbl for layer 0 ----------------
__global__ void patch_embed_k(const float* __restrict__ x,
                              const float* __restrict__ pe_w,
                              const float* __restrict__ pe_b,
                              const float* __restrict__ cls,
                              const float* __restrict__ pos,
                              float* __restrict__ residual, float* __restrict__ hidden,
                              float* __restrict__ dbl)
{
    __shared__ float xp[4][256];
    int g0 = blockIdx.x * 4;
    int c = threadIdx.x;                  // 0..191
    for (int i = blockIdx.x * 192 + c; i < 2 * NTOK * 44; i += 401 * 192)
        dbl[i] = 0.f;
    #pragma unroll
    for (int j = 0; j < 4; j++) {
        int g = g0 + j;
        int b = g / LSEQ, t = g % LSEQ;
        if (t != 0) {
            int p = t - 1, pi = p / 200, pj = p % 200;
            for (int i = c; i < 256; i += 192) {
                int pp = i >> 4, qq = i & 15;
                xp[j][i] = x[((size_t)(b * 32 + pi * 16 + pp)) * 3200 + pj * 16 + qq];
            }
        }
    }
    __syncthreads();
    float acc[4] = {0.f, 0.f, 0.f, 0.f};
    for (int k = 0; k < 256; k++) {
        float w = pe_w[c * 256 + k];
        #pragma unroll
        for (int j = 0; j < 4; j++) acc[j] += xp[j][k] * w;
    }
    #pragma unroll
    for (int j = 0; j < 4; j++) {
        int g = g0 + j;
        int t = g % LSEQ;
        float v = (t == 0) ? cls[c] : (acc[j] + pe_b[c]);
        v += pos[t * DM + c];
        residual[(size_t)g * DM + c] = v;
        hidden[(size_t)g * DM + c] = v;
    }
}

// ---------------- fused prenorm + xz GEMM + conv + xx + dbl partial ----------------
// Phase 1 (all blocks): r = resin+hidden (bn==0 writes resout); per-row rms;
//   xz = (r*rms*nw) @ ipw^T (64x64 tile, R4-proven inner loop).
// Phases 2-4 (x-half blocks, bn<DI only): recompute 6 halo xz rows; causal conv
//   fwd+bwd in LDS -> xx; partial dbl = xx_tile @ xpw-slice via atomics (6-way split-K).
// grid (12, 26) x 256.
__global__ __launch_bounds__(256) void gemm_xz_k(
    const float* __restrict__ resin, const float* __restrict__ hidden,
    float* __restrict__ resout, const float* __restrict__ nw,
    const float* __restrict__ ipw,
    const float* __restrict__ cw, const float* __restrict__ cb,
    const float* __restrict__ xpw,
    float* __restrict__ xz, float* __restrict__ xx, float* __restrict__ dbl)
{
    __shared__ float pool[13952];
    __shared__ float srms[64];
    __shared__ float ps[64][4];
    __shared__ float hrms[6];
    float* Asp    = pool;                 // [48][68]  (phase 1)
    float* Wsp    = pool + 3264;          // [48][68]  (phase 1)
    float* xs     = pool;                 // [70][64]  (phases 2-3; overlays Asp/Wsp)
    float* hstage = pool + 4480;          // [6][192]
    float* xxf    = pool + 5632;          // [64][65]
    float* xxb    = pool + 9792;          // [64][65]
    float* w44    = pool;                 // [44][65]  (phase 4; overlays xs)

    int tid = threadIdx.x;
    int bn = blockIdx.x * 64;
    int bm = blockIdx.y * 64;
    int rr = tid >> 2, q = tid & 3;          // row 0..63, quarter 0..3
    int m = bm + rr;
    float rv[4][12];                          // this thread's 48 channels of row rr
    float s = 0.f;
    if (m < NTOK) {
        const float* rp = resin + (size_t)m * DM;
        const float* hp = hidden + (size_t)m * DM;
        #pragma unroll
        for (int c = 0; c < 4; c++) {
            int base = c * 48 + q * 12;
            #pragma unroll
            for (int i = 0; i < 12; i += 4) {
                float4 a = *(const float4*)&rp[base + i];
                float4 b = *(const float4*)&hp[base + i];
                float r0 = a.x + b.x, r1 = a.y + b.y, r2 = a.z + b.z, r3 = a.w + b.w;
                rv[c][i] = r0; rv[c][i + 1] = r1; rv[c][i + 2] = r2; rv[c][i + 3] = r3;
                s += r0 * r0 + r1 * r1 + r2 * r2 + r3 * r3;
            }
        }
        if (bn == 0) {
            float* op = resout + (size_t)m * DM;
            #pragma unroll
            for (int c = 0; c < 4; c++) {
                int base = c * 48 + q * 12;
                #pragma unroll
                for (int i = 0; i < 12; i += 4)
                    *(float4*)&op[base + i] =
                        make_float4(rv[c][i], rv[c][i + 1], rv[c][i + 2], rv[c][i + 3]);
            }
        }
    } else {
        #pragma unroll
        for (int c = 0; c < 4; c++)
            #pragma unroll
            for (int i = 0; i < 12; i++) rv[c][i] = 0.f;
    }
    ps[rr][q] = s;
    __syncthreads();
    if (q == 0) {
        float tot = ps[rr][0] + ps[rr][1] + ps[rr][2] + ps[rr][3];
        srms[rr] = rsqrtf(tot * (1.f / (float)DM) + 1e-5f);
    }
    __syncthreads();

    int orow = (tid >> 4) * 4;
    int ocol = (tid & 15) * 4;
    int sk = q * 12;                          // staging K-offset within chunk
    float acc[4][4] = {};
    for (int c = 0; c < 4; c++) {
        float rs = srms[rr];
        #pragma unroll
        for (int i = 0; i < 12; i++)
            Asp[(sk + i) * 68 + rr] = rv[c][i] * rs * nw[c * 48 + sk + i];
        const float* wp = ipw + (size_t)(bn + rr) * DM + c * 48 + sk;
        #pragma unroll
        for (int i = 0; i < 12; i++)
            Wsp[(sk + i) * 68 + rr] = wp[i];
        __syncthreads();
        #pragma unroll
        for (int kk = 0; kk < 48; kk++) {
            float4 a = *(const float4*)&Asp[kk * 68 + orow];
            float4 w = *(const float4*)&Wsp[kk * 68 + ocol];
            acc[0][0] += a.x * w.x; acc[0][1] += a.x * w.y; acc[0][2] += a.x * w.z; acc[0][3] += a.x * w.w;
            acc[1][0] += a.y * w.x; acc[1][1] += a.y * w.y; acc[1][2] += a.y * w.z; acc[1][3] += a.y * w.w;
            acc[2][0] += a.z * w.x; acc[2][1] += a.z * w.y; acc[2][2] += a.z * w.z; acc[2][3] += a.z * w.w;
            acc[3][0] += a.w * w.x; acc[3][1] += a.w * w.y; acc[3][2] += a.w * w.z; acc[3][3] += a.w * w.w;
        }
        __syncthreads();
    }
    // epilogue: write xz (global) and xs (LDS tile, rows 3..66; zeros for invalid rows)
    #pragma unroll
    for (int i = 0; i < 4; i++) {
        int mm = bm + orow + i;
        float4 v = make_float4(acc[i][0], acc[i][1], acc[i][2], acc[i][3]);
        *(float4*)&xs[(3 + orow + i) * 64 + ocol] = v;
        if (mm < NTOK)
            *(float4*)&xz[(size_t)mm * (2 * DI) + bn + ocol] = v;
    }
    if (bn >= DI) return;                     // z-half blocks are done
    // ---- phase 2: halo xz rows (tokens bm-3..bm-1, bm+64..bm+66) ----
    for (int i2 = tid; i2 < 6 * 192; i2 += 256) {
        int hr = i2 / 192, k = i2 - hr * 192;
        int mh = (hr < 3) ? (bm - 3 + hr) : (bm + 61 + hr);
        float v = 0.f;
        if (mh >= 0 && mh < NTOK)
            v = resin[(size_t)mh * DM + k] + hidden[(size_t)mh * DM + k];
        hstage[i2] = v;
    }
    __syncthreads();
    if (tid < 6) {
        float s2 = 0.f;
        for (int k = 0; k < 192; k++) { float v = hstage[tid * 192 + k]; s2 += v * v; }
        hrms[tid] = rsqrtf(s2 * (1.f / (float)DM) + 1e-5f);
    }
    __syncthreads();
    for (int i2 = tid; i2 < 6 * 192; i2 += 256) {
        int hr = i2 / 192, k = i2 - hr * 192;
        hstage[i2] = hstage[i2] * hrms[hr] * nw[k];
    }
    __syncthreads();
    for (int e = tid; e < 6 * 64; e += 256) {
        int hr = e >> 6, cl = e & 63;
        const float* wp = ipw + (size_t)(bn + cl) * DM;
        const float* ap = hstage + hr * 192;
        float dsum = 0.f;
        #pragma unroll 8
        for (int k = 0; k < 192; k++) dsum += ap[k] * wp[k];
        xs[((hr < 3) ? hr : (hr + 64)) * 64 + cl] = dsum;
    }
    __syncthreads();
    // ---- phase 3: causal conv fwd + bwd -> xx (global) and xxf/xxb (LDS) ----
    #pragma unroll
    for (int i = 0; i < 4; i++) {
        int mr = bm + orow + i;
        if (mr >= NTOK) {
            #pragma unroll
            for (int j = 0; j < 4; j++) {
                xxf[(orow + i) * 65 + ocol + j] = 0.f;
                xxb[(orow + i) * 65 + ocol + j] = 0.f;
            }
            continue;
        }
        int b = mr / LSEQ, t = mr - b * LSEQ;
        int xr = 3 + orow + i;
        float outf[4], outb[4];
        #pragma unroll
        for (int j = 0; j < 4; j++) {
            int ch = bn + ocol + j;
            float af = cb[ch], ab = af;
            #pragma unroll
            for (int jt = 0; jt < 4; jt++) {
                float w = cw[ch * 4 + jt];
                if (t - 3 + jt >= 0)        af += w * xs[(xr - 3 + jt) * 64 + ocol + j];
                if (t + 3 - jt <= LSEQ - 1) ab += w * xs[(xr + 3 - jt) * 64 + ocol + j];
            }
            outf[j] = silu_f(af); outb[j] = silu_f(ab);
            xxf[(orow + i) * 65 + ocol + j] = outf[j];
            xxb[(orow + i) * 65 + ocol + j] = outb[j];
        }
        *(float4*)&xx[(size_t)mr * DI + bn + ocol] =
            make_float4(outf[0], outf[1], outf[2], outf[3]);
        size_t mb = (size_t)(NTOK + b * LSEQ + (LSEQ - 1 - t));
        *(float4*)&xx[mb * DI + bn + ocol] =
            make_float4(outb[0], outb[1], outb[2], outb[3]);
    }
    __syncthreads();
    // ---- phase 4: dbl partial (this block's 64-channel K-slice), 6-way split-K atomics ----
    for (int e = tid; e < 44 * 64; e += 256) {
        int n = e >> 6, kk = e & 63;
        w44[n * 65 + kk] = xpw[(size_t)n * DI + bn + kk];
    }
    __syncthreads();
    for (int e = tid; e < 128 * 44; e += 256) {
        int row = e / 44, n = e - row * 44;
        int r6 = row & 63;
        int mr = bm + r6;
        if (mr >= NTOK) continue;
        const float* A = (row < 64) ? &xxf[r6 * 65] : &xxb[r6 * 65];
        const float* W = &w44[n * 65];
        float s4 = 0.f;
        #pragma unroll 8
        for (int kk = 0; kk < 64; kk++) s4 += A[kk] * W[kk];
        size_t mo;
        if (row < 64) mo = (size_t)mr;
        else { int b = mr / LSEQ, t = mr - b * LSEQ; mo = (size_t)(NTOK + b * LSEQ + (LSEQ - 1 - t)); }
        atomicAdd(&dbl[mo * 44 + n], s4);
    }
}

// ---------------- scan pass 1: xx from global, local scan + chunk product ----------------
// grid (24, NC-1, 8) — 2880 blocks. Also zeroes hidden for outproj atomics.
__global__ __launch_bounds__(256) void scan_part_k(
    const float* __restrict__ xx, const float* __restrict__ dbl,
    const float* __restrict__ dtw, const float* __restrict__ dtb,
    const float* __restrict__ A_log, const float* __restrict__ A_b_log,
    float* __restrict__ hloc, float* __restrict__ Pc,
    float* __restrict__ hidden)
{
    __shared__ float sdbl[TCH][28];       // pass 1 never reads C (cols 28..43)
    __shared__ float sdt[TCH][16];
    __shared__ float sxx[TCH][16];
    __shared__ float sw[16][12];
    __shared__ float sb2[16];
    int dblk = blockIdx.x, chunk = blockIdx.y;
    int db = blockIdx.z;
    int dir = db >> 2, b = db & 3;
    int tid = threadIdx.x;
    {
        int bid = (db * (NC - 1) + chunk) * 24 + dblk;
        for (int i = bid * 256 + tid; i < NTOK * DM; i += 2880 * 256)
            hidden[i] = 0.f;
    }
    int d0 = dblk * 16;
    int t0 = chunk * TCH;
    size_t dof44 = (size_t)db * LSEQ * 44;
    size_t dofx = (size_t)(dir * NTOK + b * LSEQ) * DI;
    for (int i = tid; i < TCH * 28; i += 256) {
        int t = i / 28, cc = i - t * 28;
        sdbl[t][cc] = dbl[dof44 + (size_t)(t0 + t) * 44 + cc];
    }
    if (tid < 192) { int d = tid / 12, r = tid - d * 12; sw[d][r] = dtw[(size_t)(d0 + d) * 12 + r]; }
    if (tid < 16) sb2[tid] = dtb[d0 + tid];
    for (int i = tid; i < TCH * 16; i += 256) {
        int t = i >> 4, d = i & 15;
        sxx[t][d] = xx[dofx + (size_t)(t0 + t) * DI + d0 + d];
    }
    __syncthreads();
    for (int i = tid; i < TCH * 16; i += 256) {
        int t = i >> 4, d = i & 15;
        float a2 = sb2[d];
        #pragma unroll
        for (int r = 0; r < 12; r++) a2 += sdbl[t][r] * sw[d][r];
        sdt[t][d] = (a2 > 15.f) ? a2 : __logf(1.f + __expf(a2));
    }
    __syncthreads();
    int wave = tid >> 6, lane = tid & 63;
    int dsub = wave * 4 + (lane >> 4);
    int n = lane & 15;
    const float* Al = dir ? A_b_log : A_log;
    float Aval = -__expf(Al[(d0 + dsub) * DS + n]);
    float h = 0.f, P = 1.f;
    #pragma unroll
    for (int i = 0; i < TCH; i++) {
        float dtv = sdt[i][dsub];
        float xv  = sxx[i][dsub];
        float Bv  = sdbl[i][12 + n];
        float dA = __expf(dtv * Aval);
        h = dA * h + (dtv * xv) * Bv;
        P *= dA;
    }
    size_t idx2 = ((size_t)db * NC + chunk) * (DI * DS) + (size_t)(d0 + dsub) * DS + n;
    hloc[idx2] = h;
    Pc[idx2] = P;
}

// ---------------- scan pass 2: xx from global, compose h_init, rescan, emit y ----------------
// grid (24, NC, 8) — 3072 blocks.
__global__ __launch_bounds__(256) void scan_fix_k(
    const float* __restrict__ xx, const float* __restrict__ dbl,
    const float* __restrict__ dtw, const float* __restrict__ dtb,
    const float* __restrict__ A_log, const float* __restrict__ A_b_log,
    const float* __restrict__ Dp,
    const float* __restrict__ hloc, const float* __restrict__ Pc,
    float* __restrict__ yraw)
{
    __shared__ float sdbl[TCH][44];
    __shared__ float sdt[TCH][16];
    __shared__ float sxx[TCH][16];
    __shared__ float sy[TCH][16];
    __shared__ float sw[16][12];
    __shared__ float sb2[16];
    int dblk = blockIdx.x, chunk = blockIdx.y;
    int db = blockIdx.z;
    int dir = db >> 2, b = db & 3;
    int tid = threadIdx.x;
    int d0 = dblk * 16;
    int t0 = chunk * TCH;
    size_t dofD = (size_t)db * LSEQ * DI;
    size_t dof44 = (size_t)db * LSEQ * 44;
    size_t dofx = (size_t)(dir * NTOK + b * LSEQ) * DI;
    for (int i = tid; i < TCH * 44; i += 256) {
        int t = i / 44, cc = i - t * 44;
        sdbl[t][cc] = ((t0 + t) < LSEQ) ? dbl[dof44 + (size_t)(t0 + t) * 44 + cc] : 0.f;
    }
    if (tid < 192) { int d = tid / 12, r = tid - d * 12; sw[d][r] = dtw[(size_t)(d0 + d) * 12 + r]; }
    if (tid < 16) sb2[tid] = dtb[d0 + tid];
    for (int i = tid; i < TCH * 16; i += 256) {
        int t = i >> 4, d = i & 15;
        int tq = t0 + t;
        sxx[t][d] = (tq < LSEQ) ? xx[dofx + (size_t)tq * DI + d0 + d] : 0.f;
    }
    __syncthreads();
    for (int i = tid; i < TCH * 16; i += 256) {
        int t = i >> 4, d = i & 15;
        float a2 = sb2[d];
        #pragma unroll
        for (int r = 0; r < 12; r++) a2 += sdbl[t][r] * sw[d][r];
        sdt[t][d] = (a2 > 15.f) ? a2 : __logf(1.f + __expf(a2));
    }
    __syncthreads();
    int wave = tid >> 6, lane = tid & 63;
    int dsub = wave * 4 + (lane >> 4);
    int n = lane & 15;
    const float* Al = dir ? A_b_log : A_log;
    float Aval = -__expf(Al[(d0 + dsub) * DS + n]);
    float Dv = Dp[d0 + dsub];
    // compose initial state: unconditional loads (always in-bounds), masked combine
    float h = 0.f;
    size_t cbase = (size_t)db * NC * (DI * DS) + (size_t)(d0 + dsub) * DS + n;
    #pragma unroll
    for (int j = 0; j < NC - 1; j++) {
        size_t idx = cbase + (size_t)j * (DI * DS);
        float pj = Pc[idx], hj = hloc[idx];
        h = (j < chunk) ? (pj * h + hj) : h;
    }
    #pragma unroll
    for (int i = 0; i < TCH; i++) {
        float dtv = sdt[i][dsub];
        float xv  = sxx[i][dsub];
        float Bv  = sdbl[i][12 + n];
        float Cv  = sdbl[i][28 + n];
        h = __expf(dtv * Aval) * h + (dtv * xv) * Bv;
        float p = h * Cv;
        p += __shfl_xor(p, 1);
        p += __shfl_xor(p, 2);
        p += __shfl_xor(p, 4);
        p += __shfl_xor(p, 8);
        if (n == 0) sy[i][dsub] = p + xv * Dv;
    }
    __syncthreads();
    int len = min(t0 + TCH, LSEQ) - t0;
    for (int idx = tid; idx < len * 16; idx += 256) {
        int t = idx >> 4, d = idx & 15;
        yraw[dofD + (size_t)(t0 + t) * DI + d0 + d] = sy[t][d];
    }
}

// ---------------- fused combine + outproj, 2-stage K (baseline-proven) ----------------
// grid (6, 51, 2) x 256. Also zeroes dbl for the NEXT layer's gemm_xz atomics.
__global__ __launch_bounds__(256) void outproj_k(
    const float* __restrict__ yraw, const float* __restrict__ xz,
    const float* __restrict__ opw, float* __restrict__ hidden,
    float* __restrict__ dbl)
{
    __shared__ float As[96][34];
    __shared__ float Ws[96][34];
    int tid = threadIdx.x;
    {
        int bid = (blockIdx.z * 51 + blockIdx.y) * 6 + blockIdx.x;
        for (int i = bid * 256 + tid; i < 2 * NTOK * 44; i += 612 * 256)
            dbl[i] = 0.f;
    }
    int bn = blockIdx.x * 32;
    int bm = blockIdx.y * 32;
    int kbase = blockIdx.z * 192;
    int row8 = tid >> 3, seg = tid & 7, k0 = seg * 24;
    float a[24], wreg[24];
    int m = bm + row8;
    if (m < NTOK) {
        int b = m / LSEQ, t = m % LSEQ;
        const float* yf = yraw + (size_t)m * DI + kbase + k0;
        const float* yb = yraw + (size_t)(NTOK + b * LSEQ + (LSEQ - 1 - t)) * DI + kbase + k0;
        const float* zp = xz + (size_t)m * (2 * DI) + DI + kbase + k0;
        #pragma unroll
        for (int i = 0; i < 24; i++) {
            float z = zp[i];
            a[i] = (yf[i] + yb[i]) * (z / (1.f + __expf(-z)));
        }
    } else {
        #pragma unroll
        for (int i = 0; i < 24; i++) a[i] = 0.f;
    }
    {
        const float* wp = opw + (size_t)(bn + row8) * DI + kbase + k0;
        #pragma unroll
        for (int i = 0; i < 24; i++) wreg[i] = wp[i];
    }
    int r0 = (tid >> 4) * 2, c0 = (tid & 15) * 2;
    float acc[2][2] = {};
    #pragma unroll
    for (int st = 0; st < 2; st++) {
        if (st) __syncthreads();
        if ((seg >> 2) == st) {
            int kb = k0 - st * 96;
            #pragma unroll
            for (int i = 0; i < 24; i++) {
                As[kb + i][row8] = a[i];
                Ws[kb + i][row8] = wreg[i];
            }
        }
        __syncthreads();
        #pragma unroll 8
        for (int kk = 0; kk < 96; kk++) {
            float2 av = *(const float2*)&As[kk][r0];
            float2 wv = *(const float2*)&Ws[kk][c0];
            acc[0][0] += av.x * wv.x; acc[0][1] += av.x * wv.y;
            acc[1][0] += av.y * wv.x; acc[1][1] += av.y * wv.y;
        }
    }
    #pragma unroll
    for (int i = 0; i < 2; i++) {
        int mm = bm + r0 + i;
        if (mm >= NTOK) continue;
        #pragma unroll
        for (int j = 0; j < 2; j++)
            atomicAdd(&hidden[(size_t)mm * DM + bn + c0 + j], acc[i][j]);
    }
}

// ---------------- final rmsnorm on token 0 + head (mode-switched output) ----------------
__global__ void final_head_k(const float* __restrict__ residual, const float* __restrict__ hidden,
                             const float* __restrict__ norm_f,
                             const float* __restrict__ head_w,
                             const float* __restrict__ head_b,
                             void* __restrict__ out,
                             const unsigned short* __restrict__ probe)
{
    __shared__ float wsum[3];
    __shared__ float hb[DM];
    int b = blockIdx.x;
    int c = threadIdx.x;
    int idx = (b * LSEQ) * DM + c;
    float r = residual[idx] + hidden[idx];
    float s = r * r;
    for (int off = 32; off > 0; off >>= 1) s += __shfl_down(s, off);
    int wave = c >> 6, lane = c & 63;
    if (lane == 0) wsum[wave] = s;
    __syncthreads();
    float tot = wsum[0] + wsum[1] + wsum[2];
    float rms = rsqrtf(tot / (float)DM + 1e-5f);
    hb[c] = r * rms * norm_f[c];
    __syncthreads();
    if (c < NCLS) {
        float acc = head_b[c];
        #pragma unroll 8
        for (int k = 0; k < DM; k++) acc += hb[k] * head_w[c * DM + k];
        if (probe[0] == 0x3F80u)
            ((__hip_bfloat16*)out)[b * NCLS + c] = __float2bfloat16(acc);
        else
            ((float*)out)[b * NCLS + c] = acc;
    }
}

extern "C" void kernel_launch(void* const* d_in, const int* in_sizes, int n_in,
                              void* d_out, int out_size, void* d_ws, size_t ws_size,
                              hipStream_t stream)
{
    (void)in_sizes; (void)n_in; (void)out_size; (void)ws_size;
    const float* x      = (const float*)d_in[0];
    const float* pe_w   = (const float*)d_in[1];
    const float* pe_b   = (const float*)d_in[2];
    const float* cls    = (const float*)d_in[3];
    const float* pos    = (const float*)d_in[4];
    const float* norm_w = (const float*)d_in[5];
    const float* ipw    = (const float*)d_in[6];
    const float* cw     = (const float*)d_in[7];
    const float* cb     = (const float*)d_in[8];
    const float* xpw    = (const float*)d_in[9];
    const float* dtw    = (const float*)d_in[10];
    const float* dtb    = (const float*)d_in[11];
    const float* A_log  = (const float*)d_in[12];
    const float* A_b_log= (const float*)d_in[13];
    const float* Dp     = (const float*)d_in[14];
    const float* opw    = (const float*)d_in[15];
    const float* norm_f = (const float*)d_in[16];
    const float* head_w = (const float*)d_in[17];
    const float* head_b = (const float*)d_in[18];
    const unsigned short* probe = (const unsigned short*)d_in[14];

    float* ws = (float*)d_ws;
    const size_t nTokDM = (size_t)NTOK * DM;
    const size_t nTokXZ = (size_t)NTOK * 2 * DI;
    const size_t nDirDI = (size_t)2 * NTOK * DI;
    const size_t nDir44 = (size_t)2 * NTOK * 44;
    const size_t nChunk = (size_t)2 * BATCH * NC * DI * DS;  // 786432
    float* resA   = ws;
    float* resB   = resA + nTokDM;
    float* hidden = resB + nTokDM;
    float* xz     = hidden + nTokDM;
    float* dbl    = xz + nTokXZ;
    float* yraw   = dbl + nDir44;
    float* hloc   = yraw + nDirDI;
    float* Pc     = hloc + nChunk;
    float* xx     = Pc + nChunk;

    patch_embed_k<<<NTOK / 4, DM, 0, stream>>>(x, pe_w, pe_b, cls, pos, resA, hidden, dbl);

    for (int l = 0; l < DEPTH; l++) {
        float* rin  = (l & 1) ? resB : resA;
        float* rout = (l & 1) ? resA : resB;

        gemm_xz_k<<<dim3(12, 26), 256, 0, stream>>>(
            rin, hidden, rout, norm_w + (size_t)l * DM,
            ipw + (size_t)l * 2 * DI * DM,
            cw + (size_t)l * DI * 4, cb + (size_t)l * DI,
            xpw + (size_t)l * 44 * DI,
            xz, xx, dbl);

        scan_part_k<<<dim3(DI / 16, NC - 1, 2 * BATCH), 256, 0, stream>>>(
            xx, dbl,
            dtw + (size_t)l * DI * DR, dtb + (size_t)l * DI,
            A_log + (size_t)l * DI * DS, A_b_log + (size_t)l * DI * DS,
            hloc, Pc, hidden);

        scan_fix_k<<<dim3(DI / 16, NC, 2 * BATCH), 256, 0, stream>>>(
            xx, dbl,
            dtw + (size_t)l * DI * DR, dtb + (size_t)l * DI,
            A_log + (size_t)l * DI * DS, A_b_log + (size_t)l * DI * DS,
            Dp + (size_t)l * DI, hloc, Pc, yraw);

        outproj_k<<<dim3(6, 51, 2), 256, 0, stream>>>(
            yraw, xz, opw + (size_t)l * DM * DI, hidden, dbl);
    }

    final_head_k<<<BATCH, DM, 0, stream>>>(resA, hidden, norm_f, head_w, head_b,
                                           d_out, probe);
}

// Round 11
// 3073.110 us; speedup vs baseline: 1.0187x; 1.0187x over previous
//
#include <hip/hip_runtime.h>
#include <hip/hip_bf16.h>

#define DEPTH 24
#define DM 192
#define DI 384
#define DS 16
#define DR 12
#define LSEQ 401
#define BATCH 4
#define NTOK (BATCH*LSEQ)          // 1604
#define NCLS 22
#define NC 16                      // scan time-chunks
#define TCH 26                     // ceil(401/16); last chunk = 11

__device__ __forceinline__ float silu_f(float x) { return x / (1.f + __expf(-x)); }

// ---------------- patch embed + cls + pos; 4 tokens per block ----------------
__global__ void patch_embed_k(const float* __restrict__ x,
                              const float* __restrict__ pe_w,
                              const float* __restrict__ pe_b,
                              const float* __restrict__ cls,
                              const float* __restrict__ pos,
                              float* __restrict__ residual, float* __restrict__ hidden)
{
    __shared__ float xp[4][256];
    int g0 = blockIdx.x * 4;
    int c = threadIdx.x;                  // 0..191
    #pragma unroll
    for (int j = 0; j < 4; j++) {
        int g = g0 + j;
        int b = g / LSEQ, t = g % LSEQ;
        if (t != 0) {
            int p = t - 1, pi = p / 200, pj = p % 200;
            for (int i = c; i < 256; i += 192) {
                int pp = i >> 4, qq = i & 15;
                xp[j][i] = x[((size_t)(b * 32 + pi * 16 + pp)) * 3200 + pj * 16 + qq];
            }
        }
    }
    __syncthreads();
    float acc[4] = {0.f, 0.f, 0.f, 0.f};
    for (int k = 0; k < 256; k++) {
        float w = pe_w[c * 256 + k];
        #pragma unroll
        for (int j = 0; j < 4; j++) acc[j] += xp[j][k] * w;
    }
    #pragma unroll
    for (int j = 0; j < 4; j++) {
        int g = g0 + j;
        int t = g % LSEQ;
        float v = (t == 0) ? cls[c] : (acc[j] + pe_b[c]);
        v += pos[t * DM + c];
        residual[(size_t)g * DM + c] = v;
        hidden[(size_t)g * DM + c] = v;
    }
}

// ---------------- fused prenorm + xz GEMM (R7-proven) ----------------
// grid (12, 26) x 256. Also zeroes dbl for xproj atomics.
__global__ __launch_bounds__(256) void gemm_xz_k(
    const float* __restrict__ resin, const float* __restrict__ hidden,
    float* __restrict__ resout, const float* __restrict__ nw,
    const float* __restrict__ ipw, float* __restrict__ xz,
    float* __restrict__ dbl)
{
    __shared__ float As[48][68];
    __shared__ float Ws[48][68];
    __shared__ float srms[64];
    __shared__ float ps[64][4];
    int tid = threadIdx.x;
    for (int i = (blockIdx.y * 12 + blockIdx.x) * 256 + tid; i < 2 * NTOK * 44; i += 312 * 256)
        dbl[i] = 0.f;
    int bn = blockIdx.x * 64;
    int bm = blockIdx.y * 64;
    int rr = tid >> 2, q = tid & 3;          // row 0..63, quarter 0..3
    int m = bm + rr;
    float rv[4][12];                          // this thread's 48 channels of row rr
    float s = 0.f;
    if (m < NTOK) {
        const float* rp = resin + (size_t)m * DM;
        const float* hp = hidden + (size_t)m * DM;
        #pragma unroll
        for (int c = 0; c < 4; c++) {
            int base = c * 48 + q * 12;
            #pragma unroll
            for (int i = 0; i < 12; i += 4) {
                float4 a = *(const float4*)&rp[base + i];
                float4 b = *(const float4*)&hp[base + i];
                float r0 = a.x + b.x, r1 = a.y + b.y, r2 = a.z + b.z, r3 = a.w + b.w;
                rv[c][i] = r0; rv[c][i + 1] = r1; rv[c][i + 2] = r2; rv[c][i + 3] = r3;
                s += r0 * r0 + r1 * r1 + r2 * r2 + r3 * r3;
            }
        }
        if (bn == 0) {
            float* op = resout + (size_t)m * DM;
            #pragma unroll
            for (int c = 0; c < 4; c++) {
                int base = c * 48 + q * 12;
                #pragma unroll
                for (int i = 0; i < 12; i += 4)
                    *(float4*)&op[base + i] =
                        make_float4(rv[c][i], rv[c][i + 1], rv[c][i + 2], rv[c][i + 3]);
            }
        }
    } else {
        #pragma unroll
        for (int c = 0; c < 4; c++)
            #pragma unroll
            for (int i = 0; i < 12; i++) rv[c][i] = 0.f;
    }
    ps[rr][q] = s;
    __syncthreads();
    if (q == 0) {
        float tot = ps[rr][0] + ps[rr][1] + ps[rr][2] + ps[rr][3];
        srms[rr] = rsqrtf(tot * (1.f / (float)DM) + 1e-5f);
    }
    __syncthreads();

    int orow = (tid >> 4) * 4;
    int ocol = (tid & 15) * 4;
    int sk = q * 12;                          // staging K-offset within chunk
    float acc[4][4] = {};
    for (int c = 0; c < 4; c++) {
        float rs = srms[rr];
        #pragma unroll
        for (int i = 0; i < 12; i++)
            As[sk + i][rr] = rv[c][i] * rs * nw[c * 48 + sk + i];
        const float* wp = ipw + (size_t)(bn + rr) * DM + c * 48 + sk;
        #pragma unroll
        for (int i = 0; i < 12; i++)
            Ws[sk + i][rr] = wp[i];
        __syncthreads();
        #pragma unroll
        for (int kk = 0; kk < 48; kk++) {
            float4 a = *(const float4*)&As[kk][orow];
            float4 w = *(const float4*)&Ws[kk][ocol];
            acc[0][0] += a.x * w.x; acc[0][1] += a.x * w.y; acc[0][2] += a.x * w.z; acc[0][3] += a.x * w.w;
            acc[1][0] += a.y * w.x; acc[1][1] += a.y * w.y; acc[1][2] += a.y * w.z; acc[1][3] += a.y * w.w;
            acc[2][0] += a.z * w.x; acc[2][1] += a.z * w.y; acc[2][2] += a.z * w.z; acc[2][3] += a.z * w.w;
            acc[3][0] += a.w * w.x; acc[3][1] += a.w * w.y; acc[3][2] += a.w * w.z; acc[3][3] += a.w * w.w;
        }
        __syncthreads();
    }
    #pragma unroll
    for (int i = 0; i < 4; i++) {
        int mm = bm + orow + i;
        if (mm >= NTOK) continue;
        *(float4*)&xz[(size_t)mm * (2 * DI) + bn + ocol] =
            make_float4(acc[i][0], acc[i][1], acc[i][2], acc[i][3]);
    }
}

// ---------------- xproj: dbl += silu(conv(xz)) @ xpw^T, split-K=4; emits xx ----------------
// grid (4, 101) x 256. Coalesced conv staging; also zeroes `hidden` for outproj atomics.
__global__ __launch_bounds__(256) void xproj_conv_k(
    const float* __restrict__ xz,
    const float* __restrict__ cw, const float* __restrict__ cb,
    const float* __restrict__ xpw, float* __restrict__ dbl,
    float* __restrict__ hidden, float* __restrict__ xx)
{
    __shared__ float As[96][33];
    __shared__ float Ws[96][48];
    int tid = threadIdx.x;
    for (int i = (blockIdx.y * 4 + blockIdx.x) * 256 + tid; i < NTOK * DM; i += 404 * 256)
        hidden[i] = 0.f;
    int kbase = blockIdx.x * 96;
    int bm = blockIdx.y * 32;
    for (int idx = tid; idx < 96 * 32; idx += 256) {
        int row = idx / 96, k = idx - row * 96;
        int m = bm + row;
        if (m < 2 * NTOK) {
            int dir = m / NTOK;
            int r = m - dir * NTOK;
            int b = r / LSEQ, t = r % LSEQ;
            int ch = kbase + k;
            float a = cb[ch];
            #pragma unroll
            for (int j = 0; j < 4; j++) {
                int tt = t - 3 + j;
                if (tt >= 0) {
                    int st = dir ? (LSEQ - 1 - tt) : tt;
                    a += cw[ch * 4 + j] * xz[((size_t)(b * LSEQ + st)) * (2 * DI) + ch];
                }
            }
            float v = silu_f(a);
            As[k][row] = v;
            xx[(size_t)m * DI + ch] = v;
        } else {
            As[k][row] = 0.f;
        }
    }
    for (int i = tid; i < 96 * 48; i += 256) {
        int k = i / 48, rr = i % 48;
        Ws[k][rr] = (rr < 44) ? xpw[(size_t)rr * DI + kbase + k] : 0.f;
    }
    __syncthreads();
    int row = tid & 31, cg = tid >> 5;
    int cbase = cg * 6;
    float acc[6] = {};
    #pragma unroll 4
    for (int kk = 0; kk < 96; kk++) {
        float a = As[kk][row];
        #pragma unroll
        for (int j = 0; j < 6; j++) acc[j] += a * Ws[kk][cbase + j];
    }
    int m = bm + row;
    if (m < 2 * NTOK) {
        #pragma unroll
        for (int j = 0; j < 6; j++) {
            int cc = cbase + j;
            if (cc < 44) atomicAdd(&dbl[(size_t)m * 44 + cc], acc[j]);
        }
    }
}

// ---------------- scan pass 1: all 16 chunks; emits dtv; local scan + chunk product ----------------
// grid (24, NC, 8) — 3072 blocks. Partial chunk 15 padded neutrally (dt=0 -> dA=1, xx=0 -> u=0).
__global__ __launch_bounds__(256) void scan_part_k(
    const float* __restrict__ xx, const float* __restrict__ dbl,
    const float* __restrict__ dtw, const float* __restrict__ dtb,
    const float* __restrict__ A_log, const float* __restrict__ A_b_log,
    float* __restrict__ hloc, float* __restrict__ Pc,
    float* __restrict__ dtv)
{
    __shared__ float sdbl[TCH][28];       // pass 1 never reads C (cols 28..43)
    __shared__ float sdt[TCH][16];
    __shared__ float sxx[TCH][16];
    __shared__ float sw[16][12];
    __shared__ float sb2[16];
    int dblk = blockIdx.x, chunk = blockIdx.y;
    int db = blockIdx.z;
    int dir = db >> 2, b = db & 3;
    int tid = threadIdx.x;
    int d0 = dblk * 16;
    int t0 = chunk * TCH;
    size_t dof44 = (size_t)db * LSEQ * 44;
    size_t dofx = (size_t)(dir * NTOK + b * LSEQ) * DI;
    size_t dofv = (size_t)db * LSEQ * DI;
    for (int i = tid; i < TCH * 28; i += 256) {
        int t = i / 28, cc = i - t * 28;
        sdbl[t][cc] = ((t0 + t) < LSEQ) ? dbl[dof44 + (size_t)(t0 + t) * 44 + cc] : 0.f;
    }
    if (tid < 192) { int d = tid / 12, r = tid - d * 12; sw[d][r] = dtw[(size_t)(d0 + d) * 12 + r]; }
    if (tid < 16) sb2[tid] = dtb[d0 + tid];
    for (int i = tid; i < TCH * 16; i += 256) {
        int t = i >> 4, d = i & 15;
        int tq = t0 + t;
        sxx[t][d] = (tq < LSEQ) ? xx[dofx + (size_t)tq * DI + d0 + d] : 0.f;
    }
    __syncthreads();
    for (int i = tid; i < TCH * 16; i += 256) {
        int t = i >> 4, d = i & 15;
        int tq = t0 + t;
        float a2 = sb2[d];
        #pragma unroll
        for (int r = 0; r < 12; r++) a2 += sdbl[t][r] * sw[d][r];
        float v = (a2 > 15.f) ? a2 : __logf(1.f + __expf(a2));
        sdt[t][d] = (tq < LSEQ) ? v : 0.f;
    }
    __syncthreads();
    // forward dt to scan_fix (coalesced 64B rows per 16-lane group)
    for (int i = tid; i < TCH * 16; i += 256) {
        int t = i >> 4, d = i & 15;
        int tq = t0 + t;
        if (tq < LSEQ) dtv[dofv + (size_t)tq * DI + d0 + d] = sdt[t][d];
    }
    int wave = tid >> 6, lane = tid & 63;
    int dsub = wave * 4 + (lane >> 4);
    int n = lane & 15;
    const float* Al = dir ? A_b_log : A_log;
    float Aval = -__expf(Al[(d0 + dsub) * DS + n]);
    float h = 0.f, P = 1.f;
    #pragma unroll
    for (int i = 0; i < TCH; i++) {
        float dtvv = sdt[i][dsub];
        float xv   = sxx[i][dsub];
        float Bv   = sdbl[i][12 + n];
        float dA = __expf(dtvv * Aval);
        h = dA * h + (dtvv * xv) * Bv;
        P *= dA;
    }
    size_t idx2 = ((size_t)db * NC + chunk) * (DI * DS) + (size_t)(d0 + dsub) * DS + n;
    hloc[idx2] = h;
    Pc[idx2] = P;
}

// ---------------- scan pass 2: dt from dtv; compose h_init, rescan, emit y ----------------
// grid (24, NC, 8) — 3072 blocks. No dt recompute; staging narrowed to B/C cols (12..43).
__global__ __launch_bounds__(256) void scan_fix_k(
    const float* __restrict__ xx, const float* __restrict__ dbl,
    const float* __restrict__ dtv,
    const float* __restrict__ A_log, const float* __restrict__ A_b_log,
    const float* __restrict__ Dp,
    const float* __restrict__ hloc, const float* __restrict__ Pc,
    float* __restrict__ yraw)
{
    __shared__ float sbc[TCH][33];        // dbl cols 12..43: B = [0..15], C = [16..31]
    __shared__ float sdt[TCH][16];
    __shared__ float sxx[TCH][16];
    __shared__ float sy[TCH][16];
    int dblk = blockIdx.x, chunk = blockIdx.y;
    int db = blockIdx.z;
    int dir = db >> 2, b = db & 3;
    int tid = threadIdx.x;
    int d0 = dblk * 16;
    int t0 = chunk * TCH;
    size_t dofD = (size_t)db * LSEQ * DI;
    size_t dof44 = (size_t)db * LSEQ * 44;
    size_t dofx = (size_t)(dir * NTOK + b * LSEQ) * DI;
    size_t dofv = (size_t)db * LSEQ * DI;
    for (int i = tid; i < TCH * 32; i += 256) {
        int t = i >> 5, cc = i & 31;
        sbc[t][cc] = ((t0 + t) < LSEQ) ? dbl[dof44 + (size_t)(t0 + t) * 44 + 12 + cc] : 0.f;
    }
    for (int i = tid; i < TCH * 16; i += 256) {
        int t = i >> 4, d = i & 15;
        int tq = t0 + t;
        sxx[t][d] = (tq < LSEQ) ? xx[dofx + (size_t)tq * DI + d0 + d] : 0.f;
        sdt[t][d] = (tq < LSEQ) ? dtv[dofv + (size_t)tq * DI + d0 + d] : 0.f;
    }
    __syncthreads();
    int wave = tid >> 6, lane = tid & 63;
    int dsub = wave * 4 + (lane >> 4);
    int n = lane & 15;
    const float* Al = dir ? A_b_log : A_log;
    float Aval = -__expf(Al[(d0 + dsub) * DS + n]);
    float Dv = Dp[d0 + dsub];
    // compose initial state: unconditional loads (always in-bounds), masked combine
    float h = 0.f;
    size_t cbase = (size_t)db * NC * (DI * DS) + (size_t)(d0 + dsub) * DS + n;
    #pragma unroll
    for (int j = 0; j < NC - 1; j++) {
        size_t idx = cbase + (size_t)j * (DI * DS);
        float pj = Pc[idx], hj = hloc[idx];
        h = (j < chunk) ? (pj * h + hj) : h;
    }
    #pragma unroll
    for (int i = 0; i < TCH; i++) {
        float dtvv = sdt[i][dsub];
        float xv   = sxx[i][dsub];
        float Bv   = sbc[i][n];
        float Cv   = sbc[i][16 + n];
        h = __expf(dtvv * Aval) * h + (dtvv * xv) * Bv;
        float p = h * Cv;
        p += __shfl_xor(p, 1);
        p += __shfl_xor(p, 2);
        p += __shfl_xor(p, 4);
        p += __shfl_xor(p, 8);
        if (n == 0) sy[i][dsub] = p + xv * Dv;
    }
    __syncthreads();
    int len = min(t0 + TCH, LSEQ) - t0;
    for (int idx = tid; idx < len * 16; idx += 256) {
        int t = idx >> 4, d = idx & 15;
        yraw[dofD + (size_t)(t0 + t) * DI + d0 + d] = sy[t][d];
    }
}

// ---------------- fused combine + outproj, 2-stage K (baseline-proven) ----------------
// grid (6, 51, 2) x 256
__global__ __launch_bounds__(256) void outproj_k(
    const float* __restrict__ yraw, const float* __restrict__ xz,
    const float* __restrict__ opw, float* __restrict__ hidden)
{
    __shared__ float As[96][34];
    __shared__ float Ws[96][34];
    int tid = threadIdx.x;
    int bn = blockIdx.x * 32;
    int bm = blockIdx.y * 32;
    int kbase = blockIdx.z * 192;
    int row8 = tid >> 3, seg = tid & 7, k0 = seg * 24;
    float a[24], wreg[24];
    int m = bm + row8;
    if (m < NTOK) {
        int b = m / LSEQ, t = m % LSEQ;
        const float* yf = yraw + (size_t)m * DI + kbase + k0;
        const float* yb = yraw + (size_t)(NTOK + b * LSEQ + (LSEQ - 1 - t)) * DI + kbase + k0;
        const float* zp = xz + (size_t)m * (2 * DI) + DI + kbase + k0;
        #pragma unroll
        for (int i = 0; i < 24; i++) {
            float z = zp[i];
            a[i] = (yf[i] + yb[i]) * (z / (1.f + __expf(-z)));
        }
    } else {
        #pragma unroll
        for (int i = 0; i < 24; i++) a[i] = 0.f;
    }
    {
        const float* wp = opw + (size_t)(bn + row8) * DI + kbase + k0;
        #pragma unroll
        for (int i = 0; i < 24; i++) wreg[i] = wp[i];
    }
    int r0 = (tid >> 4) * 2, c0 = (tid & 15) * 2;
    float acc[2][2] = {};
    #pragma unroll
    for (int st = 0; st < 2; st++) {
        if (st) __syncthreads();
        if ((seg >> 2) == st) {
            int kb = k0 - st * 96;
            #pragma unroll
            for (int i = 0; i < 24; i++) {
                As[kb + i][row8] = a[i];
                Ws[kb + i][row8] = wreg[i];
            }
        }
        __syncthreads();
        #pragma unroll 8
        for (int kk = 0; kk < 96; kk++) {
            float2 av = *(const float2*)&As[kk][r0];
            float2 wv = *(const float2*)&Ws[kk][c0];
            acc[0][0] += av.x * wv.x; acc[0][1] += av.x * wv.y;
            acc[1][0] += av.y * wv.x; acc[1][1] += av.y * wv.y;
        }
    }
    #pragma unroll
    for (int i = 0; i < 2; i++) {
        int mm = bm + r0 + i;
        if (mm >= NTOK) continue;
        #pragma unroll
        for (int j = 0; j < 2; j++)
            atomicAdd(&hidden[(size_t)mm * DM + bn + c0 + j], acc[i][j]);
    }
}

// ---------------- final rmsnorm on token 0 + head (mode-switched output) ----------------
__global__ void final_head_k(const float* __restrict__ residual, const float* __restrict__ hidden,
                             const float* __restrict__ norm_f,
                             const float* __restrict__ head_w,
                             const float* __restrict__ head_b,
                             void* __restrict__ out,
                             const unsigned short* __restrict__ probe)
{
    __shared__ float wsum[3];
    __shared__ float hb[DM];
    int b = blockIdx.x;
    int c = threadIdx.x;
    int idx = (b * LSEQ) * DM + c;
    float r = residual[idx] + hidden[idx];
    float s = r * r;
    for (int off = 32; off > 0; off >>= 1) s += __shfl_down(s, off);
    int wave = c >> 6, lane = c & 63;
    if (lane == 0) wsum[wave] = s;
    __syncthreads();
    float tot = wsum[0] + wsum[1] + wsum[2];
    float rms = rsqrtf(tot / (float)DM + 1e-5f);
    hb[c] = r * rms * norm_f[c];
    __syncthreads();
    if (c < NCLS) {
        float acc = head_b[c];
        #pragma unroll 8
        for (int k = 0; k < DM; k++) acc += hb[k] * head_w[c * DM + k];
        if (probe[0] == 0x3F80u)
            ((__hip_bfloat16*)out)[b * NCLS + c] = __float2bfloat16(acc);
        else
            ((float*)out)[b * NCLS + c] = acc;
    }
}

extern "C" void kernel_launch(void* const* d_in, const int* in_sizes, int n_in,
                              void* d_out, int out_size, void* d_ws, size_t ws_size,
                              hipStream_t stream)
{
    (void)in_sizes; (void)n_in; (void)out_size; (void)ws_size;
    const float* x      = (const float*)d_in[0];
    const float* pe_w   = (const float*)d_in[1];
    const float* pe_b   = (const float*)d_in[2];
    const float* cls    = (const float*)d_in[3];
    const float* pos    = (const float*)d_in[4];
    const float* norm_w = (const float*)d_in[5];
    const float* ipw    = (const float*)d_in[6];
    const float* cw     = (const float*)d_in[7];
    const float* cb     = (const float*)d_in[8];
    const float* xpw    = (const float*)d_in[9];
    const float* dtw    = (const float*)d_in[10];
    const float* dtb    = (const float*)d_in[11];
    const float* A_log  = (const float*)d_in[12];
    const float* A_b_log= (const float*)d_in[13];
    const float* Dp     = (const float*)d_in[14];
    const float* opw    = (const float*)d_in[15];
    const float* norm_f = (const float*)d_in[16];
    const float* head_w = (const float*)d_in[17];
    const float* head_b = (const float*)d_in[18];
    const unsigned short* probe = (const unsigned short*)d_in[14];

    float* ws = (float*)d_ws;
    const size_t nTokDM = (size_t)NTOK * DM;
    const size_t nTokXZ = (size_t)NTOK * 2 * DI;
    const size_t nDirDI = (size_t)2 * NTOK * DI;
    const size_t nDir44 = (size_t)2 * NTOK * 44;
    const size_t nChunk = (size_t)2 * BATCH * NC * DI * DS;  // 786432
    float* resA   = ws;
    float* resB   = resA + nTokDM;
    float* hidden = resB + nTokDM;
    float* xz     = hidden + nTokDM;
    float* dbl    = xz + nTokXZ;
    float* yraw   = dbl + nDir44;
    float* hloc   = yraw + nDirDI;
    float* Pc     = hloc + nChunk;
    float* xx     = Pc + nChunk;
    float* dtv    = xx + nDirDI;

    patch_embed_k<<<NTOK / 4, DM, 0, stream>>>(x, pe_w, pe_b, cls, pos, resA, hidden);

    for (int l = 0; l < DEPTH; l++) {
        float* rin  = (l & 1) ? resB : resA;
        float* rout = (l & 1) ? resA : resB;

        gemm_xz_k<<<dim3(12, 26), 256, 0, stream>>>(
            rin, hidden, rout, norm_w + (size_t)l * DM,
            ipw + (size_t)l * 2 * DI * DM, xz, dbl);

        xproj_conv_k<<<dim3(4, 101), 256, 0, stream>>>(
            xz, cw + (size_t)l * DI * 4, cb + (size_t)l * DI,
            xpw + (size_t)l * 44 * DI, dbl, hidden, xx);

        scan_part_k<<<dim3(DI / 16, NC, 2 * BATCH), 256, 0, stream>>>(
            xx, dbl,
            dtw + (size_t)l * DI * DR, dtb + (size_t)l * DI,
            A_log + (size_t)l * DI * DS, A_b_log + (size_t)l * DI * DS,
            hloc, Pc, dtv);

        scan_fix_k<<<dim3(DI / 16, NC, 2 * BATCH), 256, 0, stream>>>(
            xx, dbl, dtv,
            A_log + (size_t)l * DI * DS, A_b_log + (size_t)l * DI * DS,
            Dp + (size_t)l * DI, hloc, Pc, yraw);

        outproj_k<<<dim3(6, 51, 2), 256, 0, stream>>>(
            yraw, xz, opw + (size_t)l * DM * DI, hidden);
    }

    final_head_k<<<BATCH, DM, 0, stream>>>(resA, hidden, norm_f, head_w, head_b,
                                           d_out, probe);
}

// Round 12
// 3046.257 us; speedup vs baseline: 1.0277x; 1.0088x over previous
//
#include <hip/hip_runtime.h>
#include <hip/hip_bf16.h>

#define DEPTH 24
#define DM 192
#define DI 384
#define DS 16
#define DR 12
#define LSEQ 401
#define BATCH 4
#define NTOK (BATCH*LSEQ)          // 1604
#define NCLS 22
#define NC 16                      // scan time-chunks
#define TCH 26                     // ceil(401/16); last chunk = 11

__device__ __forceinline__ float silu_f(float x) { return x / (1.f + __expf(-x)); }

// ---------------- patch embed + cls + pos; 4 tokens per block ----------------
__global__ void patch_embed_k(const float* __restrict__ x,
                              const float* __restrict__ pe_w,
                              const float* __restrict__ pe_b,
                              const float* __restrict__ cls,
                              const float* __restrict__ pos,
                              float* __restrict__ residual, float* __restrict__ hidden)
{
    __shared__ float xp[4][256];
    int g0 = blockIdx.x * 4;
    int c = threadIdx.x;                  // 0..191
    #pragma unroll
    for (int j = 0; j < 4; j++) {
        int g = g0 + j;
        int b = g / LSEQ, t = g % LSEQ;
        if (t != 0) {
            int p = t - 1, pi = p / 200, pj = p % 200;
            for (int i = c; i < 256; i += 192) {
                int pp = i >> 4, qq = i & 15;
                xp[j][i] = x[((size_t)(b * 32 + pi * 16 + pp)) * 3200 + pj * 16 + qq];
            }
        }
    }
    __syncthreads();
    float acc[4] = {0.f, 0.f, 0.f, 0.f};
    for (int k = 0; k < 256; k++) {
        float w = pe_w[c * 256 + k];
        #pragma unroll
        for (int j = 0; j < 4; j++) acc[j] += xp[j][k] * w;
    }
    #pragma unroll
    for (int j = 0; j < 4; j++) {
        int g = g0 + j;
        int t = g % LSEQ;
        float v = (t == 0) ? cls[c] : (acc[j] + pe_b[c]);
        v += pos[t * DM + c];
        residual[(size_t)g * DM + c] = v;
        hidden[(size_t)g * DM + c] = v;
    }
}

// ---------------- fused prenorm + xz GEMM (R4-proven 64x64 tile, 68 VGPR) ----------------
// r = resin + hidden (bn==0 blocks write resout=r); rms per row computed in-block;
// xz = (r*rms*nw) @ ipw^T. 64x64 tile, 4x4/thread, K=192 in 4 chunks of 48.
// grid (12, 26) x 256. Also zeroes dbl for xproj atomics.
__global__ __launch_bounds__(256) void gemm_xz_k(
    const float* __restrict__ resin, const float* __restrict__ hidden,
    float* __restrict__ resout, const float* __restrict__ nw,
    const float* __restrict__ ipw, float* __restrict__ xz,
    float* __restrict__ dbl)
{
    __shared__ float As[48][68];
    __shared__ float Ws[48][68];
    __shared__ float srms[64];
    __shared__ float ps[64][4];
    int tid = threadIdx.x;
    // zero dbl for the xproj atomics (312 blocks cover 2*NTOK*44 = 141152 floats)
    for (int i = (blockIdx.y * 12 + blockIdx.x) * 256 + tid; i < 2 * NTOK * 44; i += 312 * 256)
        dbl[i] = 0.f;
    int bn = blockIdx.x * 64;
    int bm = blockIdx.y * 64;
    int rr = tid >> 2, q = tid & 3;          // row 0..63, quarter 0..3
    int m = bm + rr;
    float rv[4][12];                          // this thread's 48 channels of row rr
    float s = 0.f;
    if (m < NTOK) {
        const float* rp = resin + (size_t)m * DM;
        const float* hp = hidden + (size_t)m * DM;
        #pragma unroll
        for (int c = 0; c < 4; c++) {
            int base = c * 48 + q * 12;
            #pragma unroll
            for (int i = 0; i < 12; i += 4) {
                float4 a = *(const float4*)&rp[base + i];
                float4 b = *(const float4*)&hp[base + i];
                float r0 = a.x + b.x, r1 = a.y + b.y, r2 = a.z + b.z, r3 = a.w + b.w;
                rv[c][i] = r0; rv[c][i + 1] = r1; rv[c][i + 2] = r2; rv[c][i + 3] = r3;
                s += r0 * r0 + r1 * r1 + r2 * r2 + r3 * r3;
            }
        }
        if (bn == 0) {
            float* op = resout + (size_t)m * DM;
            #pragma unroll
            for (int c = 0; c < 4; c++) {
                int base = c * 48 + q * 12;
                #pragma unroll
                for (int i = 0; i < 12; i += 4)
                    *(float4*)&op[base + i] =
                        make_float4(rv[c][i], rv[c][i + 1], rv[c][i + 2], rv[c][i + 3]);
            }
        }
    } else {
        #pragma unroll
        for (int c = 0; c < 4; c++)
            #pragma unroll
            for (int i = 0; i < 12; i++) rv[c][i] = 0.f;
    }
    ps[rr][q] = s;
    __syncthreads();
    if (q == 0) {
        float tot = ps[rr][0] + ps[rr][1] + ps[rr][2] + ps[rr][3];
        srms[rr] = rsqrtf(tot * (1.f / (float)DM) + 1e-5f);
    }
    __syncthreads();

    int orow = (tid >> 4) * 4;
    int ocol = (tid & 15) * 4;
    int sk = q * 12;                          // staging K-offset within chunk
    float acc[4][4] = {};
    for (int c = 0; c < 4; c++) {
        float rs = srms[rr];
        #pragma unroll
        for (int i = 0; i < 12; i++)
            As[sk + i][rr] = rv[c][i] * rs * nw[c * 48 + sk + i];
        const float* wp = ipw + (size_t)(bn + rr) * DM + c * 48 + sk;
        #pragma unroll
        for (int i = 0; i < 12; i++)
            Ws[sk + i][rr] = wp[i];
        __syncthreads();
        #pragma unroll
        for (int kk = 0; kk < 48; kk++) {
            float4 a = *(const float4*)&As[kk][orow];
            float4 w = *(const float4*)&Ws[kk][ocol];
            acc[0][0] += a.x * w.x; acc[0][1] += a.x * w.y; acc[0][2] += a.x * w.z; acc[0][3] += a.x * w.w;
            acc[1][0] += a.y * w.x; acc[1][1] += a.y * w.y; acc[1][2] += a.y * w.z; acc[1][3] += a.y * w.w;
            acc[2][0] += a.z * w.x; acc[2][1] += a.z * w.y; acc[2][2] += a.z * w.z; acc[2][3] += a.z * w.w;
            acc[3][0] += a.w * w.x; acc[3][1] += a.w * w.y; acc[3][2] += a.w * w.z; acc[3][3] += a.w * w.w;
        }
        __syncthreads();
    }
    #pragma unroll
    for (int i = 0; i < 4; i++) {
        int mm = bm + orow + i;
        if (mm >= NTOK) continue;
        *(float4*)&xz[(size_t)mm * (2 * DI) + bn + ocol] =
            make_float4(acc[i][0], acc[i][1], acc[i][2], acc[i][3]);
    }
}

// ---------------- xproj: dbl += silu(conv(xz)) @ xpw^T, split-K=4; emits xx ----------------
// grid (4, 101) x 256. Coalesced conv staging; also zeroes `hidden` for outproj atomics.
__global__ __launch_bounds__(256) void xproj_conv_k(
    const float* __restrict__ xz,
    const float* __restrict__ cw, const float* __restrict__ cb,
    const float* __restrict__ xpw, float* __restrict__ dbl,
    float* __restrict__ hidden, float* __restrict__ xx)
{
    __shared__ float As[96][33];
    __shared__ float Ws[96][48];
    int tid = threadIdx.x;
    for (int i = (blockIdx.y * 4 + blockIdx.x) * 256 + tid; i < NTOK * DM; i += 404 * 256)
        hidden[i] = 0.f;
    int kbase = blockIdx.x * 96;
    int bm = blockIdx.y * 32;
    for (int idx = tid; idx < 96 * 32; idx += 256) {
        int row = idx / 96, k = idx - row * 96;
        int m = bm + row;
        if (m < 2 * NTOK) {
            int dir = m / NTOK;
            int r = m - dir * NTOK;
            int b = r / LSEQ, t = r % LSEQ;
            int ch = kbase + k;
            float a = cb[ch];
            #pragma unroll
            for (int j = 0; j < 4; j++) {
                int tt = t - 3 + j;
                if (tt >= 0) {
                    int st = dir ? (LSEQ - 1 - tt) : tt;
                    a += cw[ch * 4 + j] * xz[((size_t)(b * LSEQ + st)) * (2 * DI) + ch];
                }
            }
            float v = silu_f(a);
            As[k][row] = v;
            xx[(size_t)m * DI + ch] = v;
        } else {
            As[k][row] = 0.f;
        }
    }
    for (int i = tid; i < 96 * 48; i += 256) {
        int k = i / 48, rr = i % 48;
        Ws[k][rr] = (rr < 44) ? xpw[(size_t)rr * DI + kbase + k] : 0.f;
    }
    __syncthreads();
    int row = tid & 31, cg = tid >> 5;
    int cbase = cg * 6;
    float acc[6] = {};
    #pragma unroll 4
    for (int kk = 0; kk < 96; kk++) {
        float a = As[kk][row];
        #pragma unroll
        for (int j = 0; j < 6; j++) acc[j] += a * Ws[kk][cbase + j];
    }
    int m = bm + row;
    if (m < 2 * NTOK) {
        #pragma unroll
        for (int j = 0; j < 6; j++) {
            int cc = cbase + j;
            if (cc < 44) atomicAdd(&dbl[(size_t)m * 44 + cc], acc[j]);
        }
    }
}

// ---------------- scan pass 1: xx from global, local scan + chunk product ----------------
// grid (24, NC-1, 8) — 2880 blocks.
__global__ __launch_bounds__(256) void scan_part_k(
    const float* __restrict__ xx, const float* __restrict__ dbl,
    const float* __restrict__ dtw, const float* __restrict__ dtb,
    const float* __restrict__ A_log, const float* __restrict__ A_b_log,
    float* __restrict__ hloc, float* __restrict__ Pc)
{
    __shared__ float sdbl[TCH][28];       // pass 1 never reads C (cols 28..43)
    __shared__ float sdt[TCH][16];
    __shared__ float sxx[TCH][16];
    __shared__ float sw[16][12];
    __shared__ float sb2[16];
    int dblk = blockIdx.x, chunk = blockIdx.y;
    int db = blockIdx.z;
    int dir = db >> 2, b = db & 3;
    int tid = threadIdx.x;
    int d0 = dblk * 16;
    int t0 = chunk * TCH;
    size_t dof44 = (size_t)db * LSEQ * 44;
    size_t dofx = (size_t)(dir * NTOK + b * LSEQ) * DI;
    for (int i = tid; i < TCH * 28; i += 256) {
        int t = i / 28, cc = i - t * 28;
        sdbl[t][cc] = dbl[dof44 + (size_t)(t0 + t) * 44 + cc];
    }
    if (tid < 192) { int d = tid / 12, r = tid - d * 12; sw[d][r] = dtw[(size_t)(d0 + d) * 12 + r]; }
    if (tid < 16) sb2[tid] = dtb[d0 + tid];
    for (int i = tid; i < TCH * 16; i += 256) {
        int t = i >> 4, d = i & 15;
        sxx[t][d] = xx[dofx + (size_t)(t0 + t) * DI + d0 + d];
    }
    __syncthreads();
    for (int i = tid; i < TCH * 16; i += 256) {
        int t = i >> 4, d = i & 15;
        float a2 = sb2[d];
        #pragma unroll
        for (int r = 0; r < 12; r++) a2 += sdbl[t][r] * sw[d][r];
        sdt[t][d] = (a2 > 15.f) ? a2 : __logf(1.f + __expf(a2));
    }
    __syncthreads();
    int wave = tid >> 6, lane = tid & 63;
    int dsub = wave * 4 + (lane >> 4);
    int n = lane & 15;
    const float* Al = dir ? A_b_log : A_log;
    float Aval = -__expf(Al[(d0 + dsub) * DS + n]);
    float h = 0.f, P = 1.f;
    #pragma unroll
    for (int i = 0; i < TCH; i++) {
        float dtv = sdt[i][dsub];
        float xv  = sxx[i][dsub];
        float Bv  = sdbl[i][12 + n];
        float dA = __expf(dtv * Aval);
        h = dA * h + (dtv * xv) * Bv;
        P *= dA;
    }
    size_t idx2 = ((size_t)db * NC + chunk) * (DI * DS) + (size_t)(d0 + dsub) * DS + n;
    hloc[idx2] = h;
    Pc[idx2] = P;
}

// ---------------- scan pass 2: xx from global, compose h_init, rescan, emit y ----------------
// grid (24, NC, 8) — 3072 blocks.
__global__ __launch_bounds__(256) void scan_fix_k(
    const float* __restrict__ xx, const float* __restrict__ dbl,
    const float* __restrict__ dtw, const float* __restrict__ dtb,
    const float* __restrict__ A_log, const float* __restrict__ A_b_log,
    const float* __restrict__ Dp,
    const float* __restrict__ hloc, const float* __restrict__ Pc,
    float* __restrict__ yraw)
{
    __shared__ float sdbl[TCH][44];
    __shared__ float sdt[TCH][16];
    __shared__ float sxx[TCH][16];
    __shared__ float sy[TCH][16];
    __shared__ float sw[16][12];
    __shared__ float sb2[16];
    int dblk = blockIdx.x, chunk = blockIdx.y;
    int db = blockIdx.z;
    int dir = db >> 2, b = db & 3;
    int tid = threadIdx.x;
    int d0 = dblk * 16;
    int t0 = chunk * TCH;
    size_t dofD = (size_t)db * LSEQ * DI;
    size_t dof44 = (size_t)db * LSEQ * 44;
    size_t dofx = (size_t)(dir * NTOK + b * LSEQ) * DI;
    for (int i = tid; i < TCH * 44; i += 256) {
        int t = i / 44, cc = i - t * 44;
        sdbl[t][cc] = ((t0 + t) < LSEQ) ? dbl[dof44 + (size_t)(t0 + t) * 44 + cc] : 0.f;
    }
    if (tid < 192) { int d = tid / 12, r = tid - d * 12; sw[d][r] = dtw[(size_t)(d0 + d) * 12 + r]; }
    if (tid < 16) sb2[tid] = dtb[d0 + tid];
    for (int i = tid; i < TCH * 16; i += 256) {
        int t = i >> 4, d = i & 15;
        int tq = t0 + t;
        sxx[t][d] = (tq < LSEQ) ? xx[dofx + (size_t)tq * DI + d0 + d] : 0.f;
    }
    __syncthreads();
    for (int i = tid; i < TCH * 16; i += 256) {
        int t = i >> 4, d = i & 15;
        float a2 = sb2[d];
        #pragma unroll
        for (int r = 0; r < 12; r++) a2 += sdbl[t][r] * sw[d][r];
        sdt[t][d] = (a2 > 15.f) ? a2 : __logf(1.f + __expf(a2));
    }
    __syncthreads();
    int wave = tid >> 6, lane = tid & 63;
    int dsub = wave * 4 + (lane >> 4);
    int n = lane & 15;
    const float* Al = dir ? A_b_log : A_log;
    float Aval = -__expf(Al[(d0 + dsub) * DS + n]);
    float Dv = Dp[d0 + dsub];
    // compose initial state: unconditional loads (always in-bounds), masked combine
    float h = 0.f;
    size_t cbase = (size_t)db * NC * (DI * DS) + (size_t)(d0 + dsub) * DS + n;
    #pragma unroll
    for (int j = 0; j < NC - 1; j++) {
        size_t idx = cbase + (size_t)j * (DI * DS);
        float pj = Pc[idx], hj = hloc[idx];
        h = (j < chunk) ? (pj * h + hj) : h;
    }
    #pragma unroll
    for (int i = 0; i < TCH; i++) {
        float dtv = sdt[i][dsub];
        float xv  = sxx[i][dsub];
        float Bv  = sdbl[i][12 + n];
        float Cv  = sdbl[i][28 + n];
        h = __expf(dtv * Aval) * h + (dtv * xv) * Bv;
        float p = h * Cv;
        p += __shfl_xor(p, 1);
        p += __shfl_xor(p, 2);
        p += __shfl_xor(p, 4);
        p += __shfl_xor(p, 8);
        if (n == 0) sy[i][dsub] = p + xv * Dv;
    }
    __syncthreads();
    int len = min(t0 + TCH, LSEQ) - t0;
    for (int idx = tid; idx < len * 16; idx += 256) {
        int t = idx >> 4, d = idx & 15;
        yraw[dofD + (size_t)(t0 + t) * DI + d0 + d] = sy[t][d];
    }
}

// ---------------- fused combine + outproj, 2-stage K (baseline-proven) ----------------
// grid (6, 51, 2) x 256
__global__ __launch_bounds__(256) void outproj_k(
    const float* __restrict__ yraw, const float* __restrict__ xz,
    const float* __restrict__ opw, float* __restrict__ hidden)
{
    __shared__ float As[96][34];
    __shared__ float Ws[96][34];
    int tid = threadIdx.x;
    int bn = blockIdx.x * 32;
    int bm = blockIdx.y * 32;
    int kbase = blockIdx.z * 192;
    int row8 = tid >> 3, seg = tid & 7, k0 = seg * 24;
    float a[24], wreg[24];
    int m = bm + row8;
    if (m < NTOK) {
        int b = m / LSEQ, t = m % LSEQ;
        const float* yf = yraw + (size_t)m * DI + kbase + k0;
        const float* yb = yraw + (size_t)(NTOK + b * LSEQ + (LSEQ - 1 - t)) * DI + kbase + k0;
        const float* zp = xz + (size_t)m * (2 * DI) + DI + kbase + k0;
        #pragma unroll
        for (int i = 0; i < 24; i++) {
            float z = zp[i];
            a[i] = (yf[i] + yb[i]) * (z / (1.f + __expf(-z)));
        }
    } else {
        #pragma unroll
        for (int i = 0; i < 24; i++) a[i] = 0.f;
    }
    {
        const float* wp = opw + (size_t)(bn + row8) * DI + kbase + k0;
        #pragma unroll
        for (int i = 0; i < 24; i++) wreg[i] = wp[i];
    }
    int r0 = (tid >> 4) * 2, c0 = (tid & 15) * 2;
    float acc[2][2] = {};
    #pragma unroll
    for (int st = 0; st < 2; st++) {
        if (st) __syncthreads();
        if ((seg >> 2) == st) {
            int kb = k0 - st * 96;
            #pragma unroll
            for (int i = 0; i < 24; i++) {
                As[kb + i][row8] = a[i];
                Ws[kb + i][row8] = wreg[i];
            }
        }
        __syncthreads();
        #pragma unroll 8
        for (int kk = 0; kk < 96; kk++) {
            float2 av = *(const float2*)&As[kk][r0];
            float2 wv = *(const float2*)&Ws[kk][c0];
            acc[0][0] += av.x * wv.x; acc[0][1] += av.x * wv.y;
            acc[1][0] += av.y * wv.x; acc[1][1] += av.y * wv.y;
        }
    }
    #pragma unroll
    for (int i = 0; i < 2; i++) {
        int mm = bm + r0 + i;
        if (mm >= NTOK) continue;
        #pragma unroll
        for (int j = 0; j < 2; j++)
            atomicAdd(&hidden[(size_t)mm * DM + bn + c0 + j], acc[i][j]);
    }
}

// ---------------- final rmsnorm on token 0 + head (mode-switched output) ----------------
__global__ void final_head_k(const float* __restrict__ residual, const float* __restrict__ hidden,
                             const float* __restrict__ norm_f,
                             const float* __restrict__ head_w,
                             const float* __restrict__ head_b,
                             void* __restrict__ out,
                             const unsigned short* __restrict__ probe)
{
    __shared__ float wsum[3];
    __shared__ float hb[DM];
    int b = blockIdx.x;
    int c = threadIdx.x;
    int idx = (b * LSEQ) * DM + c;
    float r = residual[idx] + hidden[idx];
    float s = r * r;
    for (int off = 32; off > 0; off >>= 1) s += __shfl_down(s, off);
    int wave = c >> 6, lane = c & 63;
    if (lane == 0) wsum[wave] = s;
    __syncthreads();
    float tot = wsum[0] + wsum[1] + wsum[2];
    float rms = rsqrtf(tot / (float)DM + 1e-5f);
    hb[c] = r * rms * norm_f[c];
    __syncthreads();
    if (c < NCLS) {
        float acc = head_b[c];
        #pragma unroll 8
        for (int k = 0; k < DM; k++) acc += hb[k] * head_w[c * DM + k];
        if (probe[0] == 0x3F80u)
            ((__hip_bfloat16*)out)[b * NCLS + c] = __float2bfloat16(acc);
        else
            ((float*)out)[b * NCLS + c] = acc;
    }
}

extern "C" void kernel_launch(void* const* d_in, const int* in_sizes, int n_in,
                              void* d_out, int out_size, void* d_ws, size_t ws_size,
                              hipStream_t stream)
{
    (void)in_sizes; (void)n_in; (void)out_size; (void)ws_size;
    const float* x      = (const float*)d_in[0];
    const float* pe_w   = (const float*)d_in[1];
    const float* pe_b   = (const float*)d_in[2];
    const float* cls    = (const float*)d_in[3];
    const float* pos    = (const float*)d_in[4];
    const float* norm_w = (const float*)d_in[5];
    const float* ipw    = (const float*)d_in[6];
    const float* cw     = (const float*)d_in[7];
    const float* cb     = (const float*)d_in[8];
    const float* xpw    = (const float*)d_in[9];
    const float* dtw    = (const float*)d_in[10];
    const float* dtb    = (const float*)d_in[11];
    const float* A_log  = (const float*)d_in[12];
    const float* A_b_log= (const float*)d_in[13];
    const float* Dp     = (const float*)d_in[14];
    const float* opw    = (const float*)d_in[15];
    const float* norm_f = (const float*)d_in[16];
    const float* head_w = (const float*)d_in[17];
    const float* head_b = (const float*)d_in[18];
    const unsigned short* probe = (const unsigned short*)d_in[14];

    float* ws = (float*)d_ws;
    const size_t nTokDM = (size_t)NTOK * DM;
    const size_t nTokXZ = (size_t)NTOK * 2 * DI;
    const size_t nDirDI = (size_t)2 * NTOK * DI;
    const size_t nDir44 = (size_t)2 * NTOK * 44;
    const size_t nChunk = (size_t)2 * BATCH * NC * DI * DS;  // 786432
    float* resA   = ws;
    float* resB   = resA + nTokDM;
    float* hidden = resB + nTokDM;
    float* xz     = hidden + nTokDM;
    float* dbl    = xz + nTokXZ;
    float* yraw   = dbl + nDir44;
    float* hloc   = yraw + nDirDI;
    float* Pc     = hloc + nChunk;
    float* xx     = Pc + nChunk;

    patch_embed_k<<<NTOK / 4, DM, 0, stream>>>(x, pe_w, pe_b, cls, pos, resA, hidden);

    for (int l = 0; l < DEPTH; l++) {
        float* rin  = (l & 1) ? resB : resA;
        float* rout = (l & 1) ? resA : resB;

        gemm_xz_k<<<dim3(12, 26), 256, 0, stream>>>(
            rin, hidden, rout, norm_w + (size_t)l * DM,
            ipw + (size_t)l * 2 * DI * DM, xz, dbl);

        xproj_conv_k<<<dim3(4, 101), 256, 0, stream>>>(
            xz, cw + (size_t)l * DI * 4, cb + (size_t)l * DI,
            xpw + (size_t)l * 44 * DI, dbl, hidden, xx);

        scan_part_k<<<dim3(DI / 16, NC - 1, 2 * BATCH), 256, 0, stream>>>(
            xx, dbl,
            dtw + (size_t)l * DI * DR, dtb + (size_t)l * DI,
            A_log + (size_t)l * DI * DS, A_b_log + (size_t)l * DI * DS,
            hloc, Pc);

        scan_fix_k<<<dim3(DI / 16, NC, 2 * BATCH), 256, 0, stream>>>(
            xx, dbl,
            dtw + (size_t)l * DI * DR, dtb + (size_t)l * DI,
            A_log + (size_t)l * DI * DS, A_b_log + (size_t)l * DI * DS,
            Dp + (size_t)l * DI, hloc, Pc, yraw);

        outproj_k<<<dim3(6, 51, 2), 256, 0, stream>>>(
            yraw, xz, opw + (size_t)l * DM * DI, hidden);
    }

    final_head_k<<<BATCH, DM, 0, stream>>>(resA, hidden, norm_f, head_w, head_b,
                                           d_out, probe);
}